// Round 2
// baseline (688.225 us; speedup 1.0000x reference)
//
#include <hip/hip_runtime.h>

// LOBRM fused recurrence on gfx950 — fp16x2 (hi+lo) split-precision MFMA.
// B=4096 rows, K=128 steps, L=64 state. 256 blocks x 256 threads.
// Block = 16-row tile; 4 waves, each owns a 16-wide N-slice with all weight
// hi/lo B-fragments in VGPRs. Activations chain through LDS as fp16 hi/lo
// pairs; state and accumulation stay fp32. 3 MFMAs per logical product
// (hh + hl + lh) give ~2^-22 relative input error — needed because the
// gated recurrence is chaotic (bf16 inputs diverged to absmax 27 in R1).

typedef __attribute__((ext_vector_type(8))) _Float16 half8;  // 8 fp16 = 4 VGPRs
typedef __attribute__((ext_vector_type(4))) float floatx4;   // MFMA C/D

#define MFMA(a, b, c) __builtin_amdgcn_mfma_f32_16x16x32_f16((a), (b), (c), 0, 0, 0)

__device__ __forceinline__ floatx4 mfma3(half8 ah, half8 al, half8 bh, half8 bl,
                                         floatx4 c) {
    c = MFMA(ah, bh, c);
    c = MFMA(ah, bl, c);
    c = MFMA(al, bh, c);
    return c;
}

__device__ __forceinline__ float tanhf_fast(float x) {
    float e = __builtin_exp2f(x * 2.8853900817779268f);  // e^{2x}
    return 1.0f - 2.0f / (e + 1.0f);                     // inf-safe: ->1 / -1
}
__device__ __forceinline__ float sigmoidf_fast(float x) {
    float e = __builtin_exp2f(x * -1.4426950408889634f); // e^{-x}
    return 1.0f / (1.0f + e);
}

struct W2 { half8 h, l; };

__global__ __launch_bounds__(256, 1)
void lobrm_fused(const float* __restrict__ data,   // (4096,64,100)
                 const int*   __restrict__ tsteps, // (4096,64)
                 const float* __restrict__ Wu1, const float* __restrict__ bu1,
                 const float* __restrict__ Wu2, const float* __restrict__ bu2,
                 const float* __restrict__ Wr1, const float* __restrict__ br1,
                 const float* __restrict__ Wr2, const float* __restrict__ br2,
                 const float* __restrict__ Wn1, const float* __restrict__ bn1,
                 const float* __restrict__ Wn2, const float* __restrict__ bn2,
                 const float* __restrict__ Wo1, const float* __restrict__ bo1,
                 const float* __restrict__ Wo2, const float* __restrict__ bo2,
                 const float* __restrict__ Wd,  const float* __restrict__ bd,
                 float* __restrict__ out)
{
    // fp16 hi/lo activation buffers. Row strides 72/136 halfs (144/272 B):
    // 16B-aligned rows for half8 (b128) loads.
    __shared__ __align__(16) _Float16 sYh [16 * 72],  sYl [16 * 72];
    __shared__ __align__(16) _Float16 sTh [16 * 72],  sTl [16 * 72];
    __shared__ __align__(16) _Float16 sHuh[16 * 72],  sHul[16 * 72];
    __shared__ __align__(16) _Float16 sHrh[16 * 72],  sHrl[16 * 72];
    __shared__ __align__(16) _Float16 sHnh[16 * 72],  sHnl[16 * 72];
    __shared__ __align__(16) _Float16 sYCh[16 * 136], sYCl[16 * 136]; // [y1|feat|0]
    __shared__ __align__(16) _Float16 sCCh[16 * 136], sCCl[16 * 136]; // [y1*r|feat|0]
    __shared__ float    sYf[16 * 68];     // fp32 prev_y (for vol path)
    __shared__ float    sWd[64];
    __shared__ float    sVol[16 * 132];   // vol per row per step
    __shared__ unsigned sFlg[16];         // apply = upd && m, per row

    const int tid   = threadIdx.x;
    const int lane  = tid & 63;
    const int wv    = tid >> 6;          // wave = N-slice
    const int col16 = lane & 15;
    const int quad  = lane >> 4;
    const int ncol  = wv * 16 + col16;   // output column 0..63
    const int rowBase = blockIdx.x * 16;

    // ---- prologue: zero state + pad columns (must stay 0 forever) ----
    for (int x = tid; x < 16 * 72; x += 256) { sYh[x] = (_Float16)0.f; sYl[x] = (_Float16)0.f; }
    for (int x = tid; x < 16 * 136; x += 256) {
        sYCh[x] = (_Float16)0.f; sYCl[x] = (_Float16)0.f;
        sCCh[x] = (_Float16)0.f; sCCl[x] = (_Float16)0.f;
    }
    for (int x = tid; x < 16 * 68; x += 256) sYf[x] = 0.f;
    if (tid < 64) sWd[tid] = Wd[tid];
    const float bdv = bd[0];

    // ---- weight hi/lo B-fragments (this wave's 16-col slice) ----
    // B-frag for 16x16x32: lane holds B[k = kb*32 + quad*8 + j][n = ncol]
    auto loadW = [&](const float* W, int Kw, int kb) -> W2 {
        W2 f;
#pragma unroll
        for (int j = 0; j < 8; ++j) {
            int k = kb * 32 + quad * 8 + j;
            float v = (k < Kw) ? W[k * 64 + ncol] : 0.0f;
            _Float16 h = (_Float16)v;
            f.h[j] = h;
            f.l[j] = (_Float16)(v - (float)h);
        }
        return f;
    };
    W2 wO1[2], wO2[2], wU2[2], wR2[2], wN2[2], wU1[4], wR1[4], wN1[4];
#pragma unroll
    for (int kb = 0; kb < 2; ++kb) {
        wO1[kb] = loadW(Wo1, 64, kb);
        wO2[kb] = loadW(Wo2, 64, kb);
        wU2[kb] = loadW(Wu2, 64, kb);
        wR2[kb] = loadW(Wr2, 64, kb);
        wN2[kb] = loadW(Wn2, 64, kb);
    }
#pragma unroll
    for (int kb = 0; kb < 4; ++kb) {
        wU1[kb] = loadW(Wu1, 114, kb);
        wR1[kb] = loadW(Wr1, 114, kb);
        wN1[kb] = loadW(Wn1, 114, kb);
    }
    const float bo1v = bo1[ncol], bo2v = bo2[ncol];
    const float bu1v = bu1[ncol], bu2v = bu2[ncol];
    const float br1v = br1[ncol], br2v = br2[ncol];
    const float bn1v = bn1[ncol], bn2v = bn2[ncol];

    // ---- presence masks (dedup == reference's presence): wave wv owns
    // rows 4wv..4wv+3 for feat loading ----
    unsigned long long mLo[4], mHi[4];
    int cnt4[4];
#pragma unroll
    for (int r4 = 0; r4 < 4; ++r4) {
        int b = rowBase + 4 * wv + r4;
        int v = tsteps[b * 64 + lane];
        unsigned long long lo = (v < 64) ? (1ull << v) : 0ull;
        unsigned long long hi = (v >= 64) ? (1ull << (v - 64)) : 0ull;
#pragma unroll
        for (int st = 1; st < 64; st <<= 1) {
            lo |= __shfl_xor(lo, st);
            hi |= __shfl_xor(hi, st);
        }
        mLo[r4] = lo; mHi[r4] = hi; cnt4[r4] = 0;
    }
    __syncthreads();

    floatx4 pc = {0.f, 0.f, 0.f, 0.f};   // fp32 state, C-layout slice

    // helper offsets for A-frag reads
    const int aOff = col16 * 72 + quad * 8;
    const int ycOff = col16 * 136 + quad * 8;

    for (int i = 0; i < 128; ++i) {
        // ---- A) issue feat global loads for this step (indep of recurrence) ----
        bool hasU[4];
        float fv[4], mv[4];
#pragma unroll
        for (int r4 = 0; r4 < 4; ++r4) {
            unsigned long long mm = (i < 64) ? (mLo[r4] >> i) : (mHi[r4] >> (i - 64));
            hasU[r4] = (mm & 1ull) != 0ull;
            fv[r4] = 0.f; mv[r4] = 0.f;
            if (hasU[r4]) {
                int b = rowBase + 4 * wv + r4;
                const float* dp = data + ((size_t)b * 64 + cnt4[r4]) * 100;
                cnt4[r4]++;
                if (lane < 50) { fv[r4] = dp[lane]; mv[r4] = dp[50 + lane]; }
            }
        }

        // ---- B) vol = prev_y @ Wd + bd (wave 0, fp32) ----
        if (wv == 0) {
            int r = lane & 15, kc = lane >> 4;
            float s = 0.f;
#pragma unroll
            for (int j = 0; j < 16; ++j) {
                int k = kc * 16 + j;
                s += sYf[r * 68 + k] * sWd[k];
            }
            s += __shfl_xor(s, 16);
            s += __shfl_xor(s, 32);
            if (lane < 16) sVol[r * 132 + i] = s + bdv;
        }

        // ---- mm1: t = tanh(y @ Wo1 + bo1) ----
        {
            half8 a0h = *(const half8*)&sYh[aOff];
            half8 a0l = *(const half8*)&sYl[aOff];
            half8 a1h = *(const half8*)&sYh[aOff + 32];
            half8 a1l = *(const half8*)&sYl[aOff + 32];
            floatx4 acc = {0.f, 0.f, 0.f, 0.f};
            acc = mfma3(a0h, a0l, wO1[0].h, wO1[0].l, acc);
            acc = mfma3(a1h, a1l, wO1[1].h, wO1[1].l, acc);
#pragma unroll
            for (int r = 0; r < 4; ++r) {
                float t = tanhf_fast(acc[r] + bo1v);
                _Float16 h = (_Float16)t;
                int idx = (quad * 4 + r) * 72 + ncol;
                sTh[idx] = h;
                sTl[idx] = (_Float16)(t - (float)h);
            }
        }
        __syncthreads();                                   // B1

        // ---- mm2: y1 = y + t @ Wo2 + bo2 ----
        floatx4 y1;
        {
            half8 a0h = *(const half8*)&sTh[aOff];
            half8 a0l = *(const half8*)&sTl[aOff];
            half8 a1h = *(const half8*)&sTh[aOff + 32];
            half8 a1l = *(const half8*)&sTl[aOff + 32];
            floatx4 acc = {0.f, 0.f, 0.f, 0.f};
            acc = mfma3(a0h, a0l, wO2[0].h, wO2[0].l, acc);
            acc = mfma3(a1h, a1l, wO2[1].h, wO2[1].l, acc);
#pragma unroll
            for (int r = 0; r < 4; ++r) {
                y1[r] = pc[r] + acc[r] + bo2v;
                _Float16 h = (_Float16)y1[r];
                int idx = (quad * 4 + r) * 136 + ncol;
                sYCh[idx] = h;
                sYCl[idx] = (_Float16)(y1[r] - (float)h);
            }
        }

        // ---- C) feat commit + flags (wave wv: rows 4wv..4wv+3) ----
#pragma unroll
        for (int r4 = 0; r4 < 4; ++r4) {
            int row = 4 * wv + r4;
            if (hasU[r4]) {
                if (lane < 50) {
                    float f = fv[r4];
                    _Float16 h = (_Float16)f;
                    _Float16 l = (_Float16)(f - (float)h);
                    int idx = row * 136 + 64 + lane;
                    sYCh[idx] = h; sYCl[idx] = l;
                    sCCh[idx] = h; sCCl[idx] = l;
                }
                float ms = mv[r4];
#pragma unroll
                for (int st = 1; st < 64; st <<= 1) ms += __shfl_xor(ms, st);
                if (lane == 0) sFlg[row] = (ms > 0.f) ? 1u : 0u;
            } else if (lane == 0) {
                sFlg[row] = 0u;
            }
        }
        __syncthreads();                                   // B2

        // ---- mm3: hu = tanh(yc@Wu1+bu1), hr = tanh(yc@Wr1+br1), K=128 ----
        {
            floatx4 aU = {0.f, 0.f, 0.f, 0.f}, aR = {0.f, 0.f, 0.f, 0.f};
#pragma unroll
            for (int kb = 0; kb < 4; ++kb) {
                half8 ah = *(const half8*)&sYCh[ycOff + kb * 32];
                half8 al = *(const half8*)&sYCl[ycOff + kb * 32];
                aU = mfma3(ah, al, wU1[kb].h, wU1[kb].l, aU);
                aR = mfma3(ah, al, wR1[kb].h, wR1[kb].l, aR);
            }
#pragma unroll
            for (int r = 0; r < 4; ++r) {
                float tu = tanhf_fast(aU[r] + bu1v);
                float tr = tanhf_fast(aR[r] + br1v);
                int idx = (quad * 4 + r) * 72 + ncol;
                _Float16 hu = (_Float16)tu, hr = (_Float16)tr;
                sHuh[idx] = hu; sHul[idx] = (_Float16)(tu - (float)hu);
                sHrh[idx] = hr; sHrl[idx] = (_Float16)(tr - (float)hr);
            }
        }
        __syncthreads();                                   // B3

        // ---- mm4: u = sig(hu@Wu2+bu2), r = sig(hr@Wr2+br2); cc = y1*r ----
        floatx4 uG;
        {
            half8 a0h = *(const half8*)&sHuh[aOff];
            half8 a0l = *(const half8*)&sHul[aOff];
            half8 a1h = *(const half8*)&sHuh[aOff + 32];
            half8 a1l = *(const half8*)&sHul[aOff + 32];
            floatx4 au = {0.f, 0.f, 0.f, 0.f};
            au = mfma3(a0h, a0l, wU2[0].h, wU2[0].l, au);
            au = mfma3(a1h, a1l, wU2[1].h, wU2[1].l, au);
            half8 b0h = *(const half8*)&sHrh[aOff];
            half8 b0l = *(const half8*)&sHrl[aOff];
            half8 b1h = *(const half8*)&sHrh[aOff + 32];
            half8 b1l = *(const half8*)&sHrl[aOff + 32];
            floatx4 ar = {0.f, 0.f, 0.f, 0.f};
            ar = mfma3(b0h, b0l, wR2[0].h, wR2[0].l, ar);
            ar = mfma3(b1h, b1l, wR2[1].h, wR2[1].l, ar);
#pragma unroll
            for (int r = 0; r < 4; ++r) {
                uG[r] = sigmoidf_fast(au[r] + bu2v);
                float rg = sigmoidf_fast(ar[r] + br2v);
                float cc = y1[r] * rg;
                _Float16 h = (_Float16)cc;
                int idx = (quad * 4 + r) * 136 + ncol;
                sCCh[idx] = h;
                sCCl[idx] = (_Float16)(cc - (float)h);
            }
        }
        __syncthreads();                                   // B4

        // ---- mm5: hn = tanh(cc @ Wn1 + bn1), K=128 ----
        {
            floatx4 aN = {0.f, 0.f, 0.f, 0.f};
#pragma unroll
            for (int kb = 0; kb < 4; ++kb) {
                half8 ah = *(const half8*)&sCCh[ycOff + kb * 32];
                half8 al = *(const half8*)&sCCl[ycOff + kb * 32];
                aN = mfma3(ah, al, wN1[kb].h, wN1[kb].l, aN);
            }
#pragma unroll
            for (int r = 0; r < 4; ++r) {
                float t = tanhf_fast(aN[r] + bn1v);
                _Float16 h = (_Float16)t;
                int idx = (quad * 4 + r) * 72 + ncol;
                sHnh[idx] = h;
                sHnl[idx] = (_Float16)(t - (float)h);
            }
        }
        __syncthreads();                                   // B5

        // ---- mm6: ns = hn@Wn2 + bn2; blend; state update ----
        {
            half8 a0h = *(const half8*)&sHnh[aOff];
            half8 a0l = *(const half8*)&sHnl[aOff];
            half8 a1h = *(const half8*)&sHnh[aOff + 32];
            half8 a1l = *(const half8*)&sHnl[aOff + 32];
            floatx4 acc = {0.f, 0.f, 0.f, 0.f};
            acc = mfma3(a0h, a0l, wN2[0].h, wN2[0].l, acc);
            acc = mfma3(a1h, a1l, wN2[1].h, wN2[1].l, acc);
#pragma unroll
            for (int r = 0; r < 4; ++r) {
                float ns = acc[r] + bn2v;
                float ny = (1.0f - uG[r]) * ns + uG[r] * y1[r];
                unsigned ap = sFlg[quad * 4 + r];          // upd && m
                float nY = ap ? ny : y1[r];                // select: NaN-safe
                pc[r] = nY;
                int rr = quad * 4 + r;
                _Float16 h = (_Float16)nY;
                sYh[rr * 72 + ncol] = h;
                sYl[rr * 72 + ncol] = (_Float16)(nY - (float)h);
                sYf[rr * 68 + ncol] = nY;
            }
        }
        __syncthreads();                                   // B6
    }

    // ---- epilogue ----
    // out0: final prev_y (fp32 from registers, C-layout)
#pragma unroll
    for (int r = 0; r < 4; ++r) {
        int b = rowBase + quad * 4 + r;
        out[(size_t)b * 64 + ncol] = pc[r];
    }
    // out1: selected_state = vol[b][clip(ts,0,126)+1]; out2: time deltas
    float* out1 = out + (size_t)4096 * 64;
    float* out2 = out1 + (size_t)4096 * 63;
#pragma unroll
    for (int r4 = 0; r4 < 4; ++r4) {
        int row = 4 * wv + r4;
        int b = rowBase + row;
        if (lane < 63) {
            int t0 = tsteps[b * 64 + lane];
            int t1 = tsteps[b * 64 + lane + 1];
            int iv = t0 < 126 ? t0 : 126;
            out1[(size_t)b * 63 + lane] = sVol[row * 132 + iv + 1];
            out2[(size_t)b * 63 + lane] = (float)(t1 - t0);
        }
    }
}

extern "C" void kernel_launch(void* const* d_in, const int* in_sizes, int n_in,
                              void* d_out, int out_size, void* d_ws, size_t ws_size,
                              hipStream_t stream) {
    const float* data   = (const float*)d_in[0];
    const int*   tsteps = (const int*)  d_in[1];
    const float* Wu1 = (const float*)d_in[2];  const float* bu1 = (const float*)d_in[3];
    const float* Wu2 = (const float*)d_in[4];  const float* bu2 = (const float*)d_in[5];
    const float* Wr1 = (const float*)d_in[6];  const float* br1 = (const float*)d_in[7];
    const float* Wr2 = (const float*)d_in[8];  const float* br2 = (const float*)d_in[9];
    const float* Wn1 = (const float*)d_in[10]; const float* bn1 = (const float*)d_in[11];
    const float* Wn2 = (const float*)d_in[12]; const float* bn2 = (const float*)d_in[13];
    const float* Wo1 = (const float*)d_in[14]; const float* bo1 = (const float*)d_in[15];
    const float* Wo2 = (const float*)d_in[16]; const float* bo2 = (const float*)d_in[17];
    const float* Wd  = (const float*)d_in[18]; const float* bd  = (const float*)d_in[19];
    float* out = (float*)d_out;

    lobrm_fused<<<dim3(256), dim3(256), 0, stream>>>(
        data, tsteps, Wu1, bu1, Wu2, bu2, Wr1, br1, Wr2, br2,
        Wn1, bn1, Wn2, bn2, Wo1, bo1, Wo2, bo2, Wd, bd, out);
}

// Round 4
// 676.377 us; speedup vs baseline: 1.0175x; 1.0175x over previous
//
#include <hip/hip_runtime.h>

// LOBRM fused recurrence on gfx950 — fp16 hi/lo split-precision MFMA, R4.
// R4 = R2 precision (hi+lo for EVERY matmul input — R3's lo-dropping
// amplified through the chaotic recurrence to absmax 6.3) + R3 latency
// structure (independent hh/hl/lh accumulator chains: dep depth 12->4 on
// K=128 mms; vol via MFMA on wave 0; pointer-advance gather).
// 256 blocks x 256 threads; block = 16-row tile; wave = 16-col N-slice.

typedef __attribute__((ext_vector_type(8))) _Float16 half8;  // 8 fp16 = 4 VGPRs
typedef __attribute__((ext_vector_type(4))) float floatx4;   // MFMA C/D

#define MFMA(a, b, c) __builtin_amdgcn_mfma_f32_16x16x32_f16((a), (b), (c), 0, 0, 0)

__device__ __forceinline__ float tanhf_fast(float x) {
    float e = __builtin_exp2f(x * 2.8853900817779268f);  // e^{2x}
    return 1.0f - 2.0f / (e + 1.0f);                     // inf-safe: ->1 / -1
}
__device__ __forceinline__ float sigmoidf_fast(float x) {
    float e = __builtin_exp2f(x * -1.4426950408889634f); // e^{-x}
    return 1.0f / (1.0f + e);
}

struct W2 { half8 h, l; };

__global__ __launch_bounds__(256, 1)
void lobrm_fused(const float* __restrict__ data,   // (4096,64,100)
                 const int*   __restrict__ tsteps, // (4096,64)
                 const float* __restrict__ Wu1, const float* __restrict__ bu1,
                 const float* __restrict__ Wu2, const float* __restrict__ bu2,
                 const float* __restrict__ Wr1, const float* __restrict__ br1,
                 const float* __restrict__ Wr2, const float* __restrict__ br2,
                 const float* __restrict__ Wn1, const float* __restrict__ bn1,
                 const float* __restrict__ Wn2, const float* __restrict__ bn2,
                 const float* __restrict__ Wo1, const float* __restrict__ bo1,
                 const float* __restrict__ Wo2, const float* __restrict__ bo2,
                 const float* __restrict__ Wd,  const float* __restrict__ bd,
                 float* __restrict__ out)
{
    // fp16 hi/lo activation buffers. Row strides 72/136 halfs: 16B-aligned.
    __shared__ __align__(16) _Float16 sYh [16 * 72],  sYl [16 * 72];
    __shared__ __align__(16) _Float16 sTh [16 * 72],  sTl [16 * 72];
    __shared__ __align__(16) _Float16 sHuh[16 * 72],  sHul[16 * 72];
    __shared__ __align__(16) _Float16 sHrh[16 * 72],  sHrl[16 * 72];
    __shared__ __align__(16) _Float16 sHnh[16 * 72],  sHnl[16 * 72];
    __shared__ __align__(16) _Float16 sYCh[16 * 136], sYCl[16 * 136]; // [y1|feat|0]
    __shared__ __align__(16) _Float16 sCCh[16 * 136], sCCl[16 * 136]; // [y1*r|feat|0]
    __shared__ float    sVol[16 * 132];   // vol per row per step
    __shared__ unsigned sFlg[16];         // apply = upd && m, per row

    const int tid   = threadIdx.x;
    const int lane  = tid & 63;
    const int wv    = tid >> 6;          // wave = N-slice
    const int col16 = lane & 15;
    const int quad  = lane >> 4;
    const int ncol  = wv * 16 + col16;   // output column 0..63
    const int rowBase = blockIdx.x * 16;

    // ---- prologue: zero state + pad regions (pads must stay 0 forever) ----
    for (int x = tid; x < 16 * 72; x += 256) {
        sYh[x] = (_Float16)0.f; sYl[x] = (_Float16)0.f;
    }
    for (int x = tid; x < 16 * 136; x += 256) {
        sYCh[x] = (_Float16)0.f; sYCl[x] = (_Float16)0.f;
        sCCh[x] = (_Float16)0.f; sCCl[x] = (_Float16)0.f;
    }
    const float bdv = bd[0];

    // ---- weight hi/lo B-fragments (this wave's 16-col slice) ----
    // B-frag for 16x16x32: lane holds B[k = kb*32 + quad*8 + j][n = ncol]
    auto loadW = [&](const float* W, int Kw, int kb) -> W2 {
        W2 f;
#pragma unroll
        for (int j = 0; j < 8; ++j) {
            int k = kb * 32 + quad * 8 + j;
            float v = (k < Kw) ? W[k * 64 + ncol] : 0.0f;
            _Float16 h = (_Float16)v;
            f.h[j] = h;
            f.l[j] = (_Float16)(v - (float)h);
        }
        return f;
    };
    W2 wO1[2], wO2[2], wU2[2], wR2[2], wN2[2], wU1[4], wR1[4], wN1[4];
#pragma unroll
    for (int kb = 0; kb < 2; ++kb) {
        wO1[kb] = loadW(Wo1, 64, kb);
        wO2[kb] = loadW(Wo2, 64, kb);
        wU2[kb] = loadW(Wu2, 64, kb);
        wR2[kb] = loadW(Wr2, 64, kb);
        wN2[kb] = loadW(Wn2, 64, kb);
    }
#pragma unroll
    for (int kb = 0; kb < 4; ++kb) {
        wU1[kb] = loadW(Wu1, 114, kb);
        wR1[kb] = loadW(Wr1, 114, kb);
        wN1[kb] = loadW(Wn1, 114, kb);
    }
    // vol B-frag (only wave 0 uses it): column 0 = Wd, cols 1..15 = 0. hi+lo.
    W2 vwd[2];
#pragma unroll
    for (int kb = 0; kb < 2; ++kb)
#pragma unroll
        for (int j = 0; j < 8; ++j) {
            int k = kb * 32 + quad * 8 + j;
            float v = (col16 == 0) ? Wd[k] : 0.0f;
            _Float16 h = (_Float16)v;
            vwd[kb].h[j] = h;
            vwd[kb].l[j] = (_Float16)(v - (float)h);
        }
    const float bo1v = bo1[ncol], bo2v = bo2[ncol];
    const float bu1v = bu1[ncol], bu2v = bu2[ncol];
    const float br1v = br1[ncol], br2v = br2[ncol];
    const float bn1v = bn1[ncol], bn2v = bn2[ncol];

    // ---- presence masks (dedup == reference's presence): wave wv owns
    // rows 4wv..4wv+3 for feat loading ----
    unsigned long long mLo[4], mHi[4];
    const float* dPtr[4];
#pragma unroll
    for (int r4 = 0; r4 < 4; ++r4) {
        int b = rowBase + 4 * wv + r4;
        int v = tsteps[b * 64 + lane];
        unsigned long long lo = (v < 64) ? (1ull << v) : 0ull;
        unsigned long long hi = (v >= 64) ? (1ull << (v - 64)) : 0ull;
#pragma unroll
        for (int st = 1; st < 64; st <<= 1) {
            lo |= __shfl_xor(lo, st);
            hi |= __shfl_xor(hi, st);
        }
        mLo[r4] = lo; mHi[r4] = hi;
        dPtr[r4] = data + (size_t)b * 6400;
    }
    __syncthreads();

    floatx4 pc = {0.f, 0.f, 0.f, 0.f};   // fp32 state, C-layout slice
    const floatx4 z = {0.f, 0.f, 0.f, 0.f};

    const int aOff  = col16 * 72 + quad * 8;   // stride-72 A-frag base
    const int aOffH = col16 * 136 + quad * 8;  // stride-136 A-frag base

    for (int i = 0; i < 128; ++i) {
        // ---- A) issue feat global loads for this step (indep of chain) ----
        bool hasU[4];
        float fv[4], mv[4];
#pragma unroll
        for (int r4 = 0; r4 < 4; ++r4) {
            unsigned long long mm = (i < 64) ? (mLo[r4] >> i) : (mHi[r4] >> (i - 64));
            hasU[r4] = (mm & 1ull) != 0ull;
            fv[r4] = 0.f; mv[r4] = 0.f;
            if (hasU[r4]) {
                const float* dp = dPtr[r4];
                dPtr[r4] = dp + 100;
                if (lane < 50) { fv[r4] = dp[lane]; mv[r4] = dp[50 + lane]; }
            }
        }

        // ---- mm1: t = tanh(y @ Wo1 + bo1); wave 0 also: vol = y @ Wd + bd ----
        {
            half8 a0h = *(const half8*)&sYh[aOff];
            half8 a0l = *(const half8*)&sYl[aOff];
            half8 a1h = *(const half8*)&sYh[aOff + 32];
            half8 a1l = *(const half8*)&sYl[aOff + 32];
            floatx4 hh = MFMA(a1h, wO1[1].h, MFMA(a0h, wO1[0].h, z));
            floatx4 hl = MFMA(a1h, wO1[1].l, MFMA(a0h, wO1[0].l, z));
            floatx4 lh = MFMA(a1l, wO1[1].h, MFMA(a0l, wO1[0].h, z));
            if (wv == 0) {
                floatx4 vhh = MFMA(a1h, vwd[1].h, MFMA(a0h, vwd[0].h, z));
                floatx4 vhl = MFMA(a1h, vwd[1].l, MFMA(a0h, vwd[0].l, z));
                floatx4 vlh = MFMA(a1l, vwd[1].h, MFMA(a0l, vwd[0].h, z));
                floatx4 v = vhh + (vhl + vlh);
                if (col16 == 0) {
#pragma unroll
                    for (int r = 0; r < 4; ++r)
                        sVol[(quad * 4 + r) * 132 + i] = v[r] + bdv;
                }
            }
            floatx4 acc = hh + (hl + lh);
#pragma unroll
            for (int r = 0; r < 4; ++r) {
                float t = tanhf_fast(acc[r] + bo1v);
                _Float16 h = (_Float16)t;
                int idx = (quad * 4 + r) * 72 + ncol;
                sTh[idx] = h;
                sTl[idx] = (_Float16)(t - (float)h);
            }
        }
        __syncthreads();                                   // B1

        // ---- mm2: y1 = y + t @ Wo2 + bo2 ----
        floatx4 y1;
        {
            half8 t0h = *(const half8*)&sTh[aOff];
            half8 t0l = *(const half8*)&sTl[aOff];
            half8 t1h = *(const half8*)&sTh[aOff + 32];
            half8 t1l = *(const half8*)&sTl[aOff + 32];
            floatx4 hh = MFMA(t1h, wO2[1].h, MFMA(t0h, wO2[0].h, z));
            floatx4 hl = MFMA(t1h, wO2[1].l, MFMA(t0h, wO2[0].l, z));
            floatx4 lh = MFMA(t1l, wO2[1].h, MFMA(t0l, wO2[0].h, z));
            floatx4 acc = hh + (hl + lh);
#pragma unroll
            for (int r = 0; r < 4; ++r) {
                y1[r] = pc[r] + acc[r] + bo2v;
                _Float16 h = (_Float16)y1[r];
                int idx = (quad * 4 + r) * 136 + ncol;
                sYCh[idx] = h;
                sYCl[idx] = (_Float16)(y1[r] - (float)h);
            }
        }

        // ---- C) feat commit (hi+lo) + flags (wave wv: rows 4wv..4wv+3) ----
#pragma unroll
        for (int r4 = 0; r4 < 4; ++r4) {
            int row = 4 * wv + r4;
            if (hasU[r4]) {
                if (lane < 50) {
                    float f = fv[r4];
                    _Float16 h = (_Float16)f;
                    _Float16 l = (_Float16)(f - (float)h);
                    int idx = row * 136 + 64 + lane;
                    sYCh[idx] = h; sYCl[idx] = l;
                    sCCh[idx] = h; sCCl[idx] = l;
                }
                float ms = mv[r4];
#pragma unroll
                for (int st = 1; st < 64; st <<= 1) ms += __shfl_xor(ms, st);
                if (lane == 0) sFlg[row] = (ms > 0.f) ? 1u : 0u;
            } else if (lane == 0) {
                sFlg[row] = 0u;
            }
        }
        __syncthreads();                                   // B2

        // ---- mm3: hu = tanh(yc@Wu1+bu1), hr = tanh(yc@Wr1+br1), K=128 ----
        {
            half8 ah0 = *(const half8*)&sYCh[aOffH];
            half8 ah1 = *(const half8*)&sYCh[aOffH + 32];
            half8 ah2 = *(const half8*)&sYCh[aOffH + 64];
            half8 ah3 = *(const half8*)&sYCh[aOffH + 96];
            half8 al0 = *(const half8*)&sYCl[aOffH];
            half8 al1 = *(const half8*)&sYCl[aOffH + 32];
            half8 al2 = *(const half8*)&sYCl[aOffH + 64];
            half8 al3 = *(const half8*)&sYCl[aOffH + 96];
            floatx4 uhh = MFMA(ah3, wU1[3].h, MFMA(ah2, wU1[2].h,
                          MFMA(ah1, wU1[1].h, MFMA(ah0, wU1[0].h, z))));
            floatx4 uhl = MFMA(ah3, wU1[3].l, MFMA(ah2, wU1[2].l,
                          MFMA(ah1, wU1[1].l, MFMA(ah0, wU1[0].l, z))));
            floatx4 ulh = MFMA(al3, wU1[3].h, MFMA(al2, wU1[2].h,
                          MFMA(al1, wU1[1].h, MFMA(al0, wU1[0].h, z))));
            floatx4 rhh = MFMA(ah3, wR1[3].h, MFMA(ah2, wR1[2].h,
                          MFMA(ah1, wR1[1].h, MFMA(ah0, wR1[0].h, z))));
            floatx4 rhl = MFMA(ah3, wR1[3].l, MFMA(ah2, wR1[2].l,
                          MFMA(ah1, wR1[1].l, MFMA(ah0, wR1[0].l, z))));
            floatx4 rlh = MFMA(al3, wR1[3].h, MFMA(al2, wR1[2].h,
                          MFMA(al1, wR1[1].h, MFMA(al0, wR1[0].h, z))));
            floatx4 aU = uhh + (uhl + ulh);
            floatx4 aR = rhh + (rhl + rlh);
#pragma unroll
            for (int r = 0; r < 4; ++r) {
                float tu = tanhf_fast(aU[r] + bu1v);
                float tr = tanhf_fast(aR[r] + br1v);
                int idx = (quad * 4 + r) * 72 + ncol;
                _Float16 hu = (_Float16)tu, hr = (_Float16)tr;
                sHuh[idx] = hu; sHul[idx] = (_Float16)(tu - (float)hu);
                sHrh[idx] = hr; sHrl[idx] = (_Float16)(tr - (float)hr);
            }
        }
        __syncthreads();                                   // B3

        // ---- mm4: u = sig(hu@Wu2+bu2), r = sig(hr@Wr2+br2); cc = y1*r ----
        floatx4 uG;
        {
            half8 u0h = *(const half8*)&sHuh[aOff];
            half8 u0l = *(const half8*)&sHul[aOff];
            half8 u1h = *(const half8*)&sHuh[aOff + 32];
            half8 u1l = *(const half8*)&sHul[aOff + 32];
            floatx4 au = MFMA(u1h, wU2[1].h, MFMA(u0h, wU2[0].h, z))
                       + (MFMA(u1h, wU2[1].l, MFMA(u0h, wU2[0].l, z))
                        + MFMA(u1l, wU2[1].h, MFMA(u0l, wU2[0].h, z)));
            half8 r0h = *(const half8*)&sHrh[aOff];
            half8 r0l = *(const half8*)&sHrl[aOff];
            half8 r1h = *(const half8*)&sHrh[aOff + 32];
            half8 r1l = *(const half8*)&sHrl[aOff + 32];
            floatx4 ar = MFMA(r1h, wR2[1].h, MFMA(r0h, wR2[0].h, z))
                       + (MFMA(r1h, wR2[1].l, MFMA(r0h, wR2[0].l, z))
                        + MFMA(r1l, wR2[1].h, MFMA(r0l, wR2[0].h, z)));
#pragma unroll
            for (int r = 0; r < 4; ++r) {
                uG[r] = sigmoidf_fast(au[r] + bu2v);
                float rg = sigmoidf_fast(ar[r] + br2v);
                float cc = y1[r] * rg;
                _Float16 h = (_Float16)cc;
                int idx = (quad * 4 + r) * 136 + ncol;
                sCCh[idx] = h;
                sCCl[idx] = (_Float16)(cc - (float)h);
            }
        }
        __syncthreads();                                   // B4

        // ---- mm5: hn = tanh(cc @ Wn1 + bn1), K=128 ----
        {
            half8 ah0 = *(const half8*)&sCCh[aOffH];
            half8 ah1 = *(const half8*)&sCCh[aOffH + 32];
            half8 ah2 = *(const half8*)&sCCh[aOffH + 64];
            half8 ah3 = *(const half8*)&sCCh[aOffH + 96];
            half8 al0 = *(const half8*)&sCCl[aOffH];
            half8 al1 = *(const half8*)&sCCl[aOffH + 32];
            half8 al2 = *(const half8*)&sCCl[aOffH + 64];
            half8 al3 = *(const half8*)&sCCl[aOffH + 96];
            floatx4 nhh = MFMA(ah3, wN1[3].h, MFMA(ah2, wN1[2].h,
                          MFMA(ah1, wN1[1].h, MFMA(ah0, wN1[0].h, z))));
            floatx4 nhl = MFMA(ah3, wN1[3].l, MFMA(ah2, wN1[2].l,
                          MFMA(ah1, wN1[1].l, MFMA(ah0, wN1[0].l, z))));
            floatx4 nlh = MFMA(al3, wN1[3].h, MFMA(al2, wN1[2].h,
                          MFMA(al1, wN1[1].h, MFMA(al0, wN1[0].h, z))));
            floatx4 aN = nhh + (nhl + nlh);
#pragma unroll
            for (int r = 0; r < 4; ++r) {
                float t = tanhf_fast(aN[r] + bn1v);
                _Float16 h = (_Float16)t;
                int idx = (quad * 4 + r) * 72 + ncol;
                sHnh[idx] = h;
                sHnl[idx] = (_Float16)(t - (float)h);
            }
        }
        __syncthreads();                                   // B5

        // ---- mm6: ns = hn@Wn2 + bn2; blend; state update ----
        {
            half8 n0h = *(const half8*)&sHnh[aOff];
            half8 n0l = *(const half8*)&sHnl[aOff];
            half8 n1h = *(const half8*)&sHnh[aOff + 32];
            half8 n1l = *(const half8*)&sHnl[aOff + 32];
            floatx4 acc = MFMA(n1h, wN2[1].h, MFMA(n0h, wN2[0].h, z))
                        + (MFMA(n1h, wN2[1].l, MFMA(n0h, wN2[0].l, z))
                         + MFMA(n1l, wN2[1].h, MFMA(n0l, wN2[0].h, z)));
#pragma unroll
            for (int r = 0; r < 4; ++r) {
                float ns = acc[r] + bn2v;
                float ny = (1.0f - uG[r]) * ns + uG[r] * y1[r];
                unsigned ap = sFlg[quad * 4 + r];          // upd && m
                float nY = ap ? ny : y1[r];                // select: NaN-safe
                pc[r] = nY;
                int rr = quad * 4 + r;
                _Float16 h = (_Float16)nY;
                sYh[rr * 72 + ncol] = h;
                sYl[rr * 72 + ncol] = (_Float16)(nY - (float)h);
            }
        }
        __syncthreads();                                   // B6
    }

    // ---- epilogue ----
#pragma unroll
    for (int r = 0; r < 4; ++r) {
        int b = rowBase + quad * 4 + r;
        out[(size_t)b * 64 + ncol] = pc[r];
    }
    float* out1 = out + (size_t)4096 * 64;
    float* out2 = out1 + (size_t)4096 * 63;
#pragma unroll
    for (int r4 = 0; r4 < 4; ++r4) {
        int row = 4 * wv + r4;
        int b = rowBase + row;
        if (lane < 63) {
            int t0 = tsteps[b * 64 + lane];
            int t1 = tsteps[b * 64 + lane + 1];
            int iv = t0 < 126 ? t0 : 126;
            out1[(size_t)b * 63 + lane] = sVol[row * 132 + iv + 1];
            out2[(size_t)b * 63 + lane] = (float)(t1 - t0);
        }
    }
}

extern "C" void kernel_launch(void* const* d_in, const int* in_sizes, int n_in,
                              void* d_out, int out_size, void* d_ws, size_t ws_size,
                              hipStream_t stream) {
    const float* data   = (const float*)d_in[0];
    const int*   tsteps = (const int*)  d_in[1];
    const float* Wu1 = (const float*)d_in[2];  const float* bu1 = (const float*)d_in[3];
    const float* Wu2 = (const float*)d_in[4];  const float* bu2 = (const float*)d_in[5];
    const float* Wr1 = (const float*)d_in[6];  const float* br1 = (const float*)d_in[7];
    const float* Wr2 = (const float*)d_in[8];  const float* br2 = (const float*)d_in[9];
    const float* Wn1 = (const float*)d_in[10]; const float* bn1 = (const float*)d_in[11];
    const float* Wn2 = (const float*)d_in[12]; const float* bn2 = (const float*)d_in[13];
    const float* Wo1 = (const float*)d_in[14]; const float* bo1 = (const float*)d_in[15];
    const float* Wo2 = (const float*)d_in[16]; const float* bo2 = (const float*)d_in[17];
    const float* Wd  = (const float*)d_in[18]; const float* bd  = (const float*)d_in[19];
    float* out = (float*)d_out;

    lobrm_fused<<<dim3(256), dim3(256), 0, stream>>>(
        data, tsteps, Wu1, bu1, Wu2, bu2, Wr1, br1, Wr2, br2,
        Wn1, bn1, Wn2, bn2, Wo1, bo1, Wo2, bo2, Wd, bd, out);
}